// Round 5
// baseline (332.146 us; speedup 1.0000x reference)
//
#include <hip/hip_runtime.h>

// MoE SwiGLU gather, bf16 MFMA grouped GEMM.
// R5 = R4 with compile fix: manual RTNE pack2 (no __hip_bfloat162 bit_cast).
// LDS double-buffer, 1 barrier/chunk, prefetch distance 2 (two reg sets),
// LDA=40 (20-dword stride -> b128 frag reads 2-way/free), 4-wave blocks with
// 32m x 64n wave tiles, phase-2 split-K x4 + atomic reduce.

#define NEXP 8
#define HDIM 2816
#define DDIM 1024
#define NPAIR 1024
#define LDA 40          // 32 bf16 + 8 pad

typedef unsigned int uint;
typedef unsigned short ushort;
typedef __attribute__((ext_vector_type(8))) short bf16x8;
typedef __attribute__((ext_vector_type(4))) float fvec4;
typedef __attribute__((ext_vector_type(4))) uint uvec4;

__device__ __forceinline__ ushort f2bf(float f) {
    uint u = __builtin_bit_cast(uint, f);
    u += 0x7fff + ((u >> 16) & 1);          // RTNE
    return (ushort)(u >> 16);
}
__device__ __forceinline__ uint pack2(float lo, float hi) {
    return (uint)f2bf(lo) | ((uint)f2bf(hi) << 16);
}

// ws: [0] counts 32B | [1024] lists 32KB | [65536] hbuf bf16 5.77MB
__global__ __launch_bounds__(1024) void route_kernel(const int* __restrict__ idx,
                                                     int* __restrict__ counts,
                                                     int* __restrict__ lists) {
    int p = threadIdx.x;
    if (p < NEXP) counts[p] = 0;     // ws re-poisoned every call
    __syncthreads();
    int e = idx[p];
    int pos = atomicAdd(&counts[e], 1);
    lists[e * NPAIR + pos] = p;
}

// ---------------- Phase 1: hbuf[p,h] = silu(x·w1)*(x·w3) ----------------
// grid (8, 44, 8), block 256 (4 waves). Tile 128m x 64h x BK32.
__global__ __launch_bounds__(256) void h_mfma(const float* __restrict__ x,
                       const float* __restrict__ w1,
                       const float* __restrict__ w3,
                       const int* __restrict__ counts,
                       const int* __restrict__ lists,
                       ushort* __restrict__ hb) {
    const int e = blockIdx.x;
    const int cnt = counts[e];
    const int m0 = blockIdx.z * 128;
    if (m0 >= cnt) return;
    const int h0 = blockIdx.y * 64;

    __shared__ ushort sA[2][128 * LDA];
    __shared__ ushort sB1[2][64 * LDA];
    __shared__ ushort sB3[2][64 * LDA];
    __shared__ int sTok[128];
    __shared__ int sPairS[128];

    const int tid = threadIdx.x;
    if (tid < 128) {
        int m = m0 + tid;
        int mc = (m < cnt) ? m : (cnt - 1);
        int p = lists[e * NPAIR + mc];
        sTok[tid] = p >> 1;                 // TOPK=2
        sPairS[tid] = (m < cnt) ? p : -1;
    }
    __syncthreads();

    const int w = tid >> 6, lane = tid & 63;
    const int l16 = lane & 15, quad = lane >> 4;
    const int ar = tid >> 1, ah = tid & 1;   // A: row 0..127, 16-fp32 half
    const int br = tid >> 2, bq = tid & 3;   // B: row 0..63, 8-fp32 quarter

    const float* xa  = x + (size_t)sTok[ar] * DDIM + ah * 16;
    const float* wb1 = w1 + (size_t)e * HDIM * DDIM + (size_t)(h0 + br) * DDIM + bq * 8;
    const float* wb3 = w3 + (size_t)e * HDIM * DDIM + (size_t)(h0 + br) * DDIM + bq * 8;

    fvec4 acc1[2][4], acc3[2][4];
    #pragma unroll
    for (int i = 0; i < 2; ++i)
        #pragma unroll
        for (int j = 0; j < 4; ++j) { acc1[i][j] = (fvec4)0.f; acc3[i][j] = (fvec4)0.f; }

    fvec4 ra[4], rb1[2], rb3[2];   // reg set A
    fvec4 qa[4], qb1[2], qb3[2];   // reg set B

    auto LOAD = [&](int kc, fvec4* a, fvec4* b1, fvec4* b3) {
        int kk = kc * 32;
        a[0] = *(const fvec4*)(xa + kk);      a[1] = *(const fvec4*)(xa + kk + 4);
        a[2] = *(const fvec4*)(xa + kk + 8);  a[3] = *(const fvec4*)(xa + kk + 12);
        b1[0] = *(const fvec4*)(wb1 + kk);    b1[1] = *(const fvec4*)(wb1 + kk + 4);
        b3[0] = *(const fvec4*)(wb3 + kk);    b3[1] = *(const fvec4*)(wb3 + kk + 4);
    };
    auto STORE = [&](int buf, const fvec4* a, const fvec4* b1, const fvec4* b3) {
        uvec4 t0 = { pack2(a[0][0],a[0][1]), pack2(a[0][2],a[0][3]),
                     pack2(a[1][0],a[1][1]), pack2(a[1][2],a[1][3]) };
        uvec4 t1 = { pack2(a[2][0],a[2][1]), pack2(a[2][2],a[2][3]),
                     pack2(a[3][0],a[3][1]), pack2(a[3][2],a[3][3]) };
        *(uvec4*)&sA[buf][ar * LDA + ah * 16]     = t0;
        *(uvec4*)&sA[buf][ar * LDA + ah * 16 + 8] = t1;
        uvec4 u1 = { pack2(b1[0][0],b1[0][1]), pack2(b1[0][2],b1[0][3]),
                     pack2(b1[1][0],b1[1][1]), pack2(b1[1][2],b1[1][3]) };
        uvec4 u3 = { pack2(b3[0][0],b3[0][1]), pack2(b3[0][2],b3[0][3]),
                     pack2(b3[1][0],b3[1][1]), pack2(b3[1][2],b3[1][3]) };
        *(uvec4*)&sB1[buf][br * LDA + bq * 8] = u1;
        *(uvec4*)&sB3[buf][br * LDA + bq * 8] = u3;
    };
    auto MFMA = [&](int buf) {
        bf16x8 bf1[4], bf3[4];
        #pragma unroll
        for (int nj = 0; nj < 4; ++nj) {
            bf1[nj] = *(const bf16x8*)&sB1[buf][(nj * 16 + l16) * LDA + quad * 8];
            bf3[nj] = *(const bf16x8*)&sB3[buf][(nj * 16 + l16) * LDA + quad * 8];
        }
        #pragma unroll
        for (int mi = 0; mi < 2; ++mi) {
            bf16x8 af = *(const bf16x8*)&sA[buf][(w * 32 + mi * 16 + l16) * LDA + quad * 8];
            #pragma unroll
            for (int nj = 0; nj < 4; ++nj) {
                acc1[mi][nj] = __builtin_amdgcn_mfma_f32_16x16x32_bf16(af, bf1[nj], acc1[mi][nj], 0, 0, 0);
                acc3[mi][nj] = __builtin_amdgcn_mfma_f32_16x16x32_bf16(af, bf3[nj], acc3[mi][nj], 0, 0, 0);
            }
        }
    };

    const int NCH = DDIM / 32;   // 32
    LOAD(0, ra, rb1, rb3);
    STORE(0, ra, rb1, rb3);
    LOAD(1, ra, rb1, rb3);
    __syncthreads();
    for (int kc = 0; kc < NCH; kc += 2) {
        int k2 = (kc + 2 < NCH) ? kc + 2 : NCH - 1;
        int k3 = (kc + 3 < NCH) ? kc + 3 : NCH - 1;
        LOAD(k2, qa, qb1, qb3);      // in flight across MFMA+STORE+barrier
        MFMA(0);
        STORE(1, ra, rb1, rb3);      // chunk kc+1
        __syncthreads();
        LOAD(k3, ra, rb1, rb3);
        MFMA(1);
        STORE(0, qa, qb1, qb3);      // chunk kc+2
        __syncthreads();
    }

    // epilogue: C/D col=l16, row=quad*4+r
    #pragma unroll
    for (int mi = 0; mi < 2; ++mi)
        #pragma unroll
        for (int r = 0; r < 4; ++r) {
            int m = w * 32 + mi * 16 + quad * 4 + r;
            int p = sPairS[m];
            if (p >= 0) {
                size_t base = (size_t)p * HDIM + h0;
                #pragma unroll
                for (int nj = 0; nj < 4; ++nj) {
                    float a = acc1[mi][nj][r];
                    float g = acc3[mi][nj][r];
                    float s = a / (1.f + __expf(-a)) * g;
                    hb[base + nj * 16 + l16] = f2bf(s);
                }
            }
        }
}

// ---------------- Phase 2: out[p,d] += hbuf[p,:]·w2[e,:,d] ----------------
// grid (8, 16, 32): (expert, 64-d tile, mb*4+splitK). block 256. BK=32.
__global__ __launch_bounds__(256) void out_mfma(const float* __restrict__ w2,
                         const int* __restrict__ counts,
                         const int* __restrict__ lists,
                         const ushort* __restrict__ hb,
                         float* __restrict__ out) {
    const int e = blockIdx.x;
    const int cnt = counts[e];
    const int mb = blockIdx.z >> 2;
    const int sk = blockIdx.z & 3;
    const int m0 = mb * 128;
    if (m0 >= cnt) return;
    const int n0 = blockIdx.y * 64;
    const int kbase = sk * (HDIM / 4);      // 704 per split = 22 chunks

    __shared__ ushort sA[2][128 * LDA];
    __shared__ ushort sB[2][64 * LDA];
    __shared__ int sPairC[128];
    __shared__ int sPairS[128];

    const int tid = threadIdx.x;
    if (tid < 128) {
        int m = m0 + tid;
        int mc = (m < cnt) ? m : (cnt - 1);
        int p = lists[e * NPAIR + mc];
        sPairC[tid] = p;
        sPairS[tid] = (m < cnt) ? p : -1;
    }
    __syncthreads();

    const int w = tid >> 6, lane = tid & 63;
    const int l16 = lane & 15, quad = lane >> 4;
    const int ar = tid >> 1, ah = tid & 1;   // A: row, 16-bf16 half
    const int kp = tid & 15, n4 = tid >> 4;  // B: k-pair 0..15, n-float4 0..15

    const ushort* ha = hb + (size_t)sPairC[ar] * HDIM + kbase + ah * 16;
    const float* wb = w2 + (size_t)e * HDIM * DDIM + (size_t)(kbase + 2 * kp) * DDIM + n0 + n4 * 4;

    fvec4 acc[2][4];
    #pragma unroll
    for (int i = 0; i < 2; ++i)
        #pragma unroll
        for (int j = 0; j < 4; ++j) acc[i][j] = (fvec4)0.f;

    uvec4 ra0, ra1; fvec4 rf0, rf1;
    uvec4 qa0, qa1; fvec4 qf0, qf1;

    auto LOAD = [&](int kc, uvec4& a0, uvec4& a1, fvec4& f0, fvec4& f1) {
        a0 = *(const uvec4*)(ha + kc * 32);
        a1 = *(const uvec4*)(ha + kc * 32 + 8);
        f0 = *(const fvec4*)(wb + (size_t)kc * 32 * DDIM);
        f1 = *(const fvec4*)(wb + (size_t)kc * 32 * DDIM + DDIM);
    };
    auto STORE = [&](int buf, const uvec4& a0, const uvec4& a1, const fvec4& f0, const fvec4& f1) {
        *(uvec4*)&sA[buf][ar * LDA + ah * 16]     = a0;
        *(uvec4*)&sA[buf][ar * LDA + ah * 16 + 8] = a1;
        #pragma unroll
        for (int j = 0; j < 4; ++j)
            *(uint*)&sB[buf][(n4 * 4 + j) * LDA + kp * 2] = pack2(f0[j], f1[j]);
    };
    auto MFMA = [&](int buf) {
        bf16x8 bfr[4];
        #pragma unroll
        for (int nj = 0; nj < 4; ++nj)
            bfr[nj] = *(const bf16x8*)&sB[buf][(nj * 16 + l16) * LDA + quad * 8];
        #pragma unroll
        for (int mi = 0; mi < 2; ++mi) {
            bf16x8 af = *(const bf16x8*)&sA[buf][(w * 32 + mi * 16 + l16) * LDA + quad * 8];
            #pragma unroll
            for (int nj = 0; nj < 4; ++nj)
                acc[mi][nj] = __builtin_amdgcn_mfma_f32_16x16x32_bf16(af, bfr[nj], acc[mi][nj], 0, 0, 0);
        }
    };

    const int NCH = (HDIM / 4) / 32;   // 22
    LOAD(0, ra0, ra1, rf0, rf1);
    STORE(0, ra0, ra1, rf0, rf1);
    LOAD(1, ra0, ra1, rf0, rf1);
    __syncthreads();
    for (int kc = 0; kc < NCH; kc += 2) {
        int k2 = (kc + 2 < NCH) ? kc + 2 : NCH - 1;
        int k3 = (kc + 3 < NCH) ? kc + 3 : NCH - 1;
        LOAD(k2, qa0, qa1, qf0, qf1);
        MFMA(0);
        STORE(1, ra0, ra1, rf0, rf1);
        __syncthreads();
        LOAD(k3, ra0, ra1, rf0, rf1);
        MFMA(1);
        STORE(0, qa0, qa1, qf0, qf1);
        __syncthreads();
    }

    #pragma unroll
    for (int mi = 0; mi < 2; ++mi)
        #pragma unroll
        for (int r = 0; r < 4; ++r) {
            int m = w * 32 + mi * 16 + quad * 4 + r;
            int p = sPairS[m];
            if (p >= 0) {
                #pragma unroll
                for (int nj = 0; nj < 4; ++nj)
                    atomicAdd(&out[(size_t)p * DDIM + n0 + nj * 16 + l16], acc[mi][nj][r]);
            }
        }
}

extern "C" void kernel_launch(void* const* d_in, const int* in_sizes, int n_in,
                              void* d_out, int out_size, void* d_ws, size_t ws_size,
                              hipStream_t stream) {
    const float* x   = (const float*)d_in[0];
    const int*   idx = (const int*)d_in[1];
    const float* w1  = (const float*)d_in[2];
    const float* w2  = (const float*)d_in[3];
    const float* w3  = (const float*)d_in[4];
    float* out = (float*)d_out;

    char* ws = (char*)d_ws;
    int*    counts = (int*)ws;
    int*    lists  = (int*)(ws + 1024);
    ushort* hbuf   = (ushort*)(ws + 65536);

    (void)hipMemsetAsync(out, 0, (size_t)out_size * sizeof(float), stream);
    route_kernel<<<1, NPAIR, 0, stream>>>(idx, counts, lists);
    h_mfma<<<dim3(NEXP, HDIM / 64, NPAIR / 128), 256, 0, stream>>>(
        x, w1, w3, counts, lists, hbuf);
    out_mfma<<<dim3(NEXP, DDIM / 64, (NPAIR / 128) * 4), 256, 0, stream>>>(
        w2, counts, lists, hbuf, out);
}